// Round 3
// baseline (381.358 us; speedup 1.0000x reference)
//
#include <hip/hip_runtime.h>
#include <hip/hip_bf16.h>
#include <cstdint>

#define B_N 64
#define C_N 2048
#define HW_N 196
#define M_N 32
#define NC_N 396
#define K_N 65536   // M_N * C_N

// ---------------------------------------------------------------------------
// K1: zpart[q][b][m][hw] = sum_{c in chunk q} x[b][c][hw] * Wa[m][c]
// grid (2 hw-tiles of 128, 64 b, 8 c-chunks of 256), block 256.
// Thread: 2 hw x 8 m. x tile in natural [c][hw] layout (lane=hw b32 reads are
// 2-way/bank = free); Wa tile [c][m] broadcast-read. Register double-buffer:
// next tile's global loads issued before compute, consumed at next store.
// ---------------------------------------------------------------------------
__global__ __launch_bounds__(256) void k1_attn_part(
    const float* __restrict__ x, const float* __restrict__ Wa,
    float* __restrict__ zpart) {
  __shared__ float xs[64 * 128];   // [c-local][hw-local] 32 KB
  __shared__ float wl[64 * 32];    // [c-local][m] 8 KB
  const int t = threadIdx.x;
  const int l = t & 63;
  const int w = t >> 6;
  const int b = blockIdx.y;
  const int hw0 = blockIdx.x * 128;
  const int cb = blockIdx.z * 256;
  const float* __restrict__ xb = x + (size_t)b * (C_N * HW_N);

  // staging geometry (invariant over the i-unroll since 256 % 32 == 0)
  const int xhq = t & 31;          // hw-quad
  const int xh  = hw0 + xhq * 4;
  const int ccb = t >> 5;          // c-local base, +8 per i
  const bool xok = (xh < HW_N);
  const int wm  = t & 31;          // m for Wa staging
  const int wcq = t >> 5;          // c-quad base, +8 per i

  float4 px[8], pw[2];
  auto loadt = [&](int ct) {
#pragma unroll
    for (int i = 0; i < 8; ++i) {
      int cc = ccb + i * 8;
      px[i] = xok ? *(const float4*)(xb + (size_t)(cb + ct + cc) * HW_N + xh)
                  : make_float4(0.f, 0.f, 0.f, 0.f);
    }
#pragma unroll
    for (int i = 0; i < 2; ++i) {
      int cq4 = wcq + i * 8;
      pw[i] = *(const float4*)(Wa + (size_t)wm * C_N + cb + ct + cq4 * 4);
    }
  };

  float accA[8], accB[8];
#pragma unroll
  for (int j = 0; j < 8; ++j) { accA[j] = 0.f; accB[j] = 0.f; }

  loadt(0);
  for (int ct = 0; ct < 256; ct += 64) {
    if (ct) __syncthreads();
#pragma unroll
    for (int i = 0; i < 8; ++i)
      *(float4*)(xs + (ccb + i * 8) * 128 + xhq * 4) = px[i];
#pragma unroll
    for (int i = 0; i < 2; ++i) {
      int c0 = (wcq + i * 8) * 4;
      wl[(c0 + 0) * 32 + wm] = pw[i].x;   // bank = wm -> 2-way, free
      wl[(c0 + 1) * 32 + wm] = pw[i].y;
      wl[(c0 + 2) * 32 + wm] = pw[i].z;
      wl[(c0 + 3) * 32 + wm] = pw[i].w;
    }
    __syncthreads();
    if (ct + 64 < 256) loadt(ct + 64);    // in flight across compute
#pragma unroll 2
    for (int cq = 0; cq < 16; ++cq) {
#pragma unroll
      for (int r = 0; r < 4; ++r) {
        const int c = cq * 4 + r;
        float fa = xs[c * 128 + l];
        float fb = xs[c * 128 + 64 + l];
        float4 w0 = *(const float4*)(wl + c * 32 + w * 8);      // broadcast
        float4 w1 = *(const float4*)(wl + c * 32 + w * 8 + 4);  // broadcast
        accA[0] = fmaf(fa, w0.x, accA[0]); accA[1] = fmaf(fa, w0.y, accA[1]);
        accA[2] = fmaf(fa, w0.z, accA[2]); accA[3] = fmaf(fa, w0.w, accA[3]);
        accA[4] = fmaf(fa, w1.x, accA[4]); accA[5] = fmaf(fa, w1.y, accA[5]);
        accA[6] = fmaf(fa, w1.z, accA[6]); accA[7] = fmaf(fa, w1.w, accA[7]);
        accB[0] = fmaf(fb, w0.x, accB[0]); accB[1] = fmaf(fb, w0.y, accB[1]);
        accB[2] = fmaf(fb, w0.z, accB[2]); accB[3] = fmaf(fb, w0.w, accB[3]);
        accB[4] = fmaf(fb, w1.x, accB[4]); accB[5] = fmaf(fb, w1.y, accB[5]);
        accB[6] = fmaf(fb, w1.z, accB[6]); accB[7] = fmaf(fb, w1.w, accB[7]);
      }
    }
  }
  const int hwA = hw0 + l;          // always < 196 (max 191)
  const int hwB = hw0 + 64 + l;
  const size_t base = ((size_t)blockIdx.z * B_N + b) * M_N;
#pragma unroll
  for (int j = 0; j < 8; ++j) {
    int m = w * 8 + j;
    zpart[(base + m) * HW_N + hwA] = accA[j];
    if (hwB < HW_N) zpart[(base + m) * HW_N + hwB] = accB[j];
  }
}

// ---------------------------------------------------------------------------
// K1b: A = sigmoid(sum_q zpart[q] + ba)
// ---------------------------------------------------------------------------
__global__ __launch_bounds__(256) void k1b_sigmoid(
    const float* __restrict__ zpart, const float* __restrict__ ba,
    float* __restrict__ A) {
  const int TOT = B_N * M_N * HW_N;       // 401408
  int idx = blockIdx.x * 256 + threadIdx.x;
  if (idx >= TOT) return;
  int m = (idx / HW_N) & (M_N - 1);
  float z = ba[m];
#pragma unroll
  for (int q = 0; q < 8; ++q) z += zpart[(size_t)q * TOT + idx];
  A[idx] = 1.f / (1.f + __expf(-z));
}

// ---------------------------------------------------------------------------
// K2: feats[b][m*C+c] = (1/196) * sum_hw x[b][c][hw] * A[b][m][hw]
// grid (8 c-tiles of 256, 64 b), block 256. Thread: 4 c x 8 m.
// A[b] resident in LDS; compute reads A as b128 (hh-quad) broadcasts.
// Register double-buffer on the x tile.
// ---------------------------------------------------------------------------
__global__ __launch_bounds__(256) void k2_bap(
    const float* __restrict__ x, const float* __restrict__ A,
    float* __restrict__ feats) {
  __shared__ float4 atf4[1568];    // A[b] flat [m][hw] (25 KB)
  __shared__ float4 xs4[32][64];   // [hh][c-quad], swizzled (32 KB)
  const int t  = threadIdx.x;
  const int cg = t & 63;
  const int m0 = (t >> 6) * 8;
  const int b  = blockIdx.y;
  const int c0 = blockIdx.x * 256;
  const float* __restrict__ xb =
      x + (size_t)b * (C_N * HW_N) + (size_t)c0 * HW_N;

  // stage A[b] (first loop barrier covers first use)
  const float4* __restrict__ A4 = (const float4*)A + (size_t)b * 1568;
#pragma unroll
  for (int i = 0; i < 7; ++i) {
    int lin = t + i * 256;
    if (lin < 1568) atf4[lin] = A4[lin];
  }
  const float* atf = (const float*)atf4;

  const int hg   = t & 7;     // hw-quad (invariant over i: 256 % 8 == 0)
  const int ccb  = t >> 3;    // c-local base, +32 per i
  float4 px[8];
  auto loadt = [&](int h0) {
    int h = h0 + hg * 4;
    bool ok = h < HW_N;       // quads at mult-of-4 are fully valid (196 % 4 == 0)
#pragma unroll
    for (int i = 0; i < 8; ++i)
      px[i] = ok ? *(const float4*)(xb + (size_t)(ccb + i * 32) * HW_N + h)
                 : make_float4(0.f, 0.f, 0.f, 0.f);
  };

  float acc[8][4];
#pragma unroll
  for (int j = 0; j < 8; ++j)
#pragma unroll
    for (int r = 0; r < 4; ++r) acc[j][r] = 0.f;

  float* xsf = (float*)xs4;

  loadt(0);
  for (int h0 = 0; h0 < HW_N; h0 += 32) {
    const int nh4 = (HW_N - h0 < 32) ? (HW_N - h0) / 4 : 8;
    __syncthreads();
#pragma unroll
    for (int i = 0; i < 8; ++i) {
      int cc = ccb + i * 32;
      int g = cc >> 2, sub = cc & 3;
#pragma unroll
      for (int r = 0; r < 4; ++r) {
        int row = hg * 4 + r;
        xsf[row * 256 + (((g ^ (row & 15)) << 2) | sub)] = ((const float*)&px[i])[r];
      }
    }
    __syncthreads();
    if (h0 + 32 < HW_N) loadt(h0 + 32);   // in flight across compute
    for (int hq = 0; hq < nh4; ++hq) {
      float4 fv[4];
#pragma unroll
      for (int r2 = 0; r2 < 4; ++r2) {
        int row = hq * 4 + r2;
        fv[r2] = xs4[row][cg ^ (row & 15)];
      }
      const int hbase = h0 + hq * 4;
#pragma unroll
      for (int j = 0; j < 8; ++j) {
        float4 a4 = *(const float4*)(atf + (m0 + j) * HW_N + hbase);  // broadcast
        acc[j][0] = fmaf(fv[0].x, a4.x, acc[j][0]);
        acc[j][1] = fmaf(fv[0].y, a4.x, acc[j][1]);
        acc[j][2] = fmaf(fv[0].z, a4.x, acc[j][2]);
        acc[j][3] = fmaf(fv[0].w, a4.x, acc[j][3]);
        acc[j][0] = fmaf(fv[1].x, a4.y, acc[j][0]);
        acc[j][1] = fmaf(fv[1].y, a4.y, acc[j][1]);
        acc[j][2] = fmaf(fv[1].z, a4.y, acc[j][2]);
        acc[j][3] = fmaf(fv[1].w, a4.y, acc[j][3]);
        acc[j][0] = fmaf(fv[2].x, a4.z, acc[j][0]);
        acc[j][1] = fmaf(fv[2].y, a4.z, acc[j][1]);
        acc[j][2] = fmaf(fv[2].z, a4.z, acc[j][2]);
        acc[j][3] = fmaf(fv[2].w, a4.z, acc[j][3]);
        acc[j][0] = fmaf(fv[3].x, a4.w, acc[j][0]);
        acc[j][1] = fmaf(fv[3].y, a4.w, acc[j][1]);
        acc[j][2] = fmaf(fv[3].z, a4.w, acc[j][2]);
        acc[j][3] = fmaf(fv[3].w, a4.w, acc[j][3]);
      }
    }
  }
  const float s = 1.f / (float)HW_N;
#pragma unroll
  for (int j = 0; j < 8; ++j) {
    float4 o = make_float4(acc[j][0] * s, acc[j][1] * s,
                           acc[j][2] * s, acc[j][3] * s);
    *(float4*)(feats + (size_t)b * K_N + (size_t)(m0 + j) * C_N + c0 + cg * 4) = o;
  }
}

// ---------------------------------------------------------------------------
// K3: partial[kc][b][n] = sum_{k in chunk} feats[b][k] * Wc[n][k]
// grid (7 n-tiles of 64, 64 k-chunks of 1024), block 256.
// Block tile 64b x 64n; thread 4x4 strided by 16. Register double-buffer.
// ---------------------------------------------------------------------------
__global__ __launch_bounds__(256) void k3_cls_part(
    const float* __restrict__ feats, const float* __restrict__ Wc,
    float* __restrict__ partial) {
  __shared__ float fs[64 * 68];   // feats tile [b][k], pad 68
  __shared__ float ws[64 * 68];   // Wc tile [n-local][k], pad 68
  const int t  = threadIdx.x;
  const int bg = t & 15;          // b = bg + 16*i
  const int ng = t >> 4;          // n = n0 + ng + 16*j
  const int n0 = blockIdx.x * 64;
  const size_t k0 = (size_t)blockIdx.y * 1024;

  const int kg   = t & 15;        // k-quad (invariant over i: 256 % 16 == 0)
  const int rowb = t >> 4;        // row base, +16 per i
  const float* fb0 = feats + k0 + kg * 4;
  const float* wb0 = Wc + k0 + kg * 4;
  size_t nrow[4];
#pragma unroll
  for (int i = 0; i < 4; ++i) {
    int n = n0 + rowb + 16 * i;
    nrow[i] = (size_t)(n < NC_N ? n : NC_N - 1) * K_N;
  }

  float4 pf[4], pw[4];
  auto loadt = [&](int ks) {
#pragma unroll
    for (int i = 0; i < 4; ++i) {
      pf[i] = *(const float4*)(fb0 + (size_t)(rowb + 16 * i) * K_N + ks * 64);
      pw[i] = *(const float4*)(wb0 + nrow[i] + ks * 64);
    }
  };

  float acc[4][4];
#pragma unroll
  for (int i = 0; i < 4; ++i)
#pragma unroll
    for (int j = 0; j < 4; ++j) acc[i][j] = 0.f;

  loadt(0);
  for (int ks = 0; ks < 16; ++ks) {
    if (ks) __syncthreads();
#pragma unroll
    for (int i = 0; i < 4; ++i) {
      *(float4*)(fs + (rowb + 16 * i) * 68 + kg * 4) = pf[i];
      *(float4*)(ws + (rowb + 16 * i) * 68 + kg * 4) = pw[i];
    }
    __syncthreads();
    if (ks + 1 < 16) loadt(ks + 1);   // in flight across compute
#pragma unroll 4
    for (int kq = 0; kq < 16; ++kq) {
      float4 fq[4], wq[4];
#pragma unroll
      for (int i = 0; i < 4; ++i)
        fq[i] = *(const float4*)(fs + (bg + 16 * i) * 68 + kq * 4);
#pragma unroll
      for (int j = 0; j < 4; ++j)
        wq[j] = *(const float4*)(ws + (ng + 16 * j) * 68 + kq * 4);
#pragma unroll
      for (int i = 0; i < 4; ++i)
#pragma unroll
        for (int j = 0; j < 4; ++j) {
          acc[i][j] = fmaf(fq[i].x, wq[j].x, acc[i][j]);
          acc[i][j] = fmaf(fq[i].y, wq[j].y, acc[i][j]);
          acc[i][j] = fmaf(fq[i].z, wq[j].z, acc[i][j]);
          acc[i][j] = fmaf(fq[i].w, wq[j].w, acc[i][j]);
        }
    }
  }
  float* po = partial + (size_t)blockIdx.y * (B_N * NC_N);
#pragma unroll
  for (int i = 0; i < 4; ++i)
#pragma unroll
    for (int j = 0; j < 4; ++j) {
      int n = n0 + ng + 16 * j;
      if (n < NC_N) po[(bg + 16 * i) * NC_N + n] = acc[i][j];
    }
}

// ---------------------------------------------------------------------------
// K4: out[b][n] = bc[n] + sum_kc partial[kc][b][n]
// ---------------------------------------------------------------------------
__global__ __launch_bounds__(256) void k4_reduce(
    const float* __restrict__ partial, const float* __restrict__ bc,
    float* __restrict__ out) {
  int idx = blockIdx.x * 256 + threadIdx.x;  // 25344 total
  if (idx >= B_N * NC_N) return;
  int n = idx % NC_N;
  float s = bc[n];
#pragma unroll 8
  for (int kc = 0; kc < 64; ++kc) s += partial[(size_t)kc * (B_N * NC_N) + idx];
  out[idx] = s;
}

// ---------------------------------------------------------------------------
extern "C" void kernel_launch(void* const* d_in, const int* in_sizes, int n_in,
                              void* d_out, int out_size, void* d_ws, size_t ws_size,
                              hipStream_t stream) {
  const float* x  = (const float*)d_in[0];
  const float* Wa = (const float*)d_in[1];
  const float* ba = (const float*)d_in[2];
  const float* Wc = (const float*)d_in[3];
  const float* bc = (const float*)d_in[4];
  float* out = (float*)d_out;

  char* ws = (char*)d_ws;
  // lifetimes: zpart [k1..k1b], A [k1b..k2], feats [k2..k3],
  // partial [k3..k4] reuses the (dead) zpart region. Peak use < 32 MiB.
  float* A       = (float*)(ws);                 // [0, 1.61 MB)
  float* zpart   = (float*)(ws + (2u  << 20));   // 8*64*32*196*4 = 12.85 MB
  float* feats   = (float*)(ws + (15u << 20));   // 64*65536*4    = 16.8 MB
  float* partial = (float*)(ws + (2u  << 20));   // 64*25344*4    = 6.49 MB
  (void)ws_size; (void)in_sizes; (void)n_in; (void)out_size;

  hipLaunchKernelGGL(k1_attn_part, dim3(2, 64, 8), dim3(256), 0, stream,
                     x, Wa, zpart);
  hipLaunchKernelGGL(k1b_sigmoid, dim3((B_N * M_N * HW_N + 255) / 256),
                     dim3(256), 0, stream, zpart, ba, A);
  hipLaunchKernelGGL(k2_bap, dim3(8, 64), dim3(256), 0, stream, x, A, feats);
  hipLaunchKernelGGL(k3_cls_part, dim3(7, 64), dim3(256), 0, stream,
                     feats, Wc, partial);
  hipLaunchKernelGGL(k4_reduce, dim3(99), dim3(256), 0, stream,
                     partial, bc, out);
}

// Round 4
// 327.638 us; speedup vs baseline: 1.1640x; 1.1640x over previous
//
#include <hip/hip_runtime.h>
#include <hip/hip_bf16.h>
#include <cstdint>

#define B_N 64
#define C_N 2048
#define HW_N 196
#define M_N 32
#define NC_N 396
#define K_N 65536   // M_N * C_N

// ---------------------------------------------------------------------------
// K1: zpart[q][b][m][hw] = sum_{c in chunk q} x[b][c][hw] * Wa[m][c]
// grid (2 hw-tiles of 128, 64 b, 8 c-chunks of 256), block 256.
// Register double-buffer in NAMED float4 regs (no arrays/lambdas — round-3's
// lambda-captured arrays spilled to scratch: WRITE_SIZE 6.8->179 MB).
// ---------------------------------------------------------------------------
__global__ __launch_bounds__(256) void k1_attn_part(
    const float* __restrict__ x, const float* __restrict__ Wa,
    float* __restrict__ zpart) {
  __shared__ float xs[64 * 128];   // [c-local][hw-local] 32 KB
  __shared__ float wl[64 * 32];    // [c-local][m] 8 KB
  const int t = threadIdx.x;
  const int l = t & 63;
  const int w = t >> 6;
  const int b = blockIdx.y;
  const int hw0 = blockIdx.x * 128;
  const int cb = blockIdx.z * 256;
  const float* __restrict__ xb = x + (size_t)b * (C_N * HW_N);

  const int xhq = t & 31;          // hw-quad
  const int xh  = hw0 + xhq * 4;
  const int ccb = t >> 5;          // c-local base, +8 per chunk
  const bool xok = (xh < HW_N);
  const int wm  = t & 31;          // m for Wa staging
  const int wcq = t >> 5;          // c-quad base, +8 for second

  float4 px0, px1, px2, px3, px4, px5, px6, px7, pw0, pw1;
  const float4 fz = make_float4(0.f, 0.f, 0.f, 0.f);

#define K1_LX(dst, i, ct)                                                     \
  dst = xok ? *(const float4*)(xb + (size_t)(cb + (ct) + ccb + (i) * 8) * HW_N + xh) : fz
#define K1_LOAD(ct)                                                           \
  K1_LX(px0, 0, ct); K1_LX(px1, 1, ct); K1_LX(px2, 2, ct); K1_LX(px3, 3, ct); \
  K1_LX(px4, 4, ct); K1_LX(px5, 5, ct); K1_LX(px6, 6, ct); K1_LX(px7, 7, ct); \
  pw0 = *(const float4*)(Wa + (size_t)wm * C_N + cb + (ct) + wcq * 4);        \
  pw1 = *(const float4*)(Wa + (size_t)wm * C_N + cb + (ct) + (wcq + 8) * 4)

  float accA[8], accB[8];
#pragma unroll
  for (int j = 0; j < 8; ++j) { accA[j] = 0.f; accB[j] = 0.f; }

  K1_LOAD(0);
  for (int ct = 0; ct < 256; ct += 64) {
    if (ct) __syncthreads();
    *(float4*)(xs + (ccb + 0 * 8) * 128 + xhq * 4) = px0;
    *(float4*)(xs + (ccb + 1 * 8) * 128 + xhq * 4) = px1;
    *(float4*)(xs + (ccb + 2 * 8) * 128 + xhq * 4) = px2;
    *(float4*)(xs + (ccb + 3 * 8) * 128 + xhq * 4) = px3;
    *(float4*)(xs + (ccb + 4 * 8) * 128 + xhq * 4) = px4;
    *(float4*)(xs + (ccb + 5 * 8) * 128 + xhq * 4) = px5;
    *(float4*)(xs + (ccb + 6 * 8) * 128 + xhq * 4) = px6;
    *(float4*)(xs + (ccb + 7 * 8) * 128 + xhq * 4) = px7;
    {
      int c0 = wcq * 4;
      wl[(c0 + 0) * 32 + wm] = pw0.x; wl[(c0 + 1) * 32 + wm] = pw0.y;
      wl[(c0 + 2) * 32 + wm] = pw0.z; wl[(c0 + 3) * 32 + wm] = pw0.w;
      int c1 = (wcq + 8) * 4;
      wl[(c1 + 0) * 32 + wm] = pw1.x; wl[(c1 + 1) * 32 + wm] = pw1.y;
      wl[(c1 + 2) * 32 + wm] = pw1.z; wl[(c1 + 3) * 32 + wm] = pw1.w;
    }
    __syncthreads();
    if (ct + 64 < 256) { K1_LOAD(ct + 64); }   // in flight across compute
#pragma unroll 2
    for (int cq = 0; cq < 16; ++cq) {
#pragma unroll
      for (int r = 0; r < 4; ++r) {
        const int c = cq * 4 + r;
        float fa = xs[c * 128 + l];
        float fb = xs[c * 128 + 64 + l];
        float4 w0 = *(const float4*)(wl + c * 32 + w * 8);      // broadcast
        float4 w1 = *(const float4*)(wl + c * 32 + w * 8 + 4);  // broadcast
        accA[0] = fmaf(fa, w0.x, accA[0]); accA[1] = fmaf(fa, w0.y, accA[1]);
        accA[2] = fmaf(fa, w0.z, accA[2]); accA[3] = fmaf(fa, w0.w, accA[3]);
        accA[4] = fmaf(fa, w1.x, accA[4]); accA[5] = fmaf(fa, w1.y, accA[5]);
        accA[6] = fmaf(fa, w1.z, accA[6]); accA[7] = fmaf(fa, w1.w, accA[7]);
        accB[0] = fmaf(fb, w0.x, accB[0]); accB[1] = fmaf(fb, w0.y, accB[1]);
        accB[2] = fmaf(fb, w0.z, accB[2]); accB[3] = fmaf(fb, w0.w, accB[3]);
        accB[4] = fmaf(fb, w1.x, accB[4]); accB[5] = fmaf(fb, w1.y, accB[5]);
        accB[6] = fmaf(fb, w1.z, accB[6]); accB[7] = fmaf(fb, w1.w, accB[7]);
      }
    }
  }
  const int hwA = hw0 + l;          // always < 196 (max 191)
  const int hwB = hw0 + 64 + l;
  const size_t base = ((size_t)blockIdx.z * B_N + b) * M_N;
#pragma unroll
  for (int j = 0; j < 8; ++j) {
    int m = w * 8 + j;
    zpart[(base + m) * HW_N + hwA] = accA[j];
    if (hwB < HW_N) zpart[(base + m) * HW_N + hwB] = accB[j];
  }
}

// ---------------------------------------------------------------------------
// K1b: A = sigmoid(sum_q zpart[q] + ba)
// ---------------------------------------------------------------------------
__global__ __launch_bounds__(256) void k1b_sigmoid(
    const float* __restrict__ zpart, const float* __restrict__ ba,
    float* __restrict__ A) {
  const int TOT = B_N * M_N * HW_N;       // 401408
  int idx = blockIdx.x * 256 + threadIdx.x;
  if (idx >= TOT) return;
  int m = (idx / HW_N) & (M_N - 1);
  float z = ba[m];
#pragma unroll
  for (int q = 0; q < 8; ++q) z += zpart[(size_t)q * TOT + idx];
  A[idx] = 1.f / (1.f + __expf(-z));
}

// ---------------------------------------------------------------------------
// K2: feats[b][m*C+c] = (1/196) * sum_hw x[b][c][hw] * A[b][m][hw]
// grid (8 c-tiles of 256, 64 b), block 256. Thread: 4 c x 8 m.
// A[b] resident in LDS; A read as b128 broadcasts. Named-reg double buffer.
// ---------------------------------------------------------------------------
__global__ __launch_bounds__(256) void k2_bap(
    const float* __restrict__ x, const float* __restrict__ A,
    float* __restrict__ feats) {
  __shared__ float4 atf4[1568];    // A[b] flat [m][hw] (25 KB)
  __shared__ float4 xs4[32][64];   // [hh][c-quad], swizzled (32 KB)
  const int t  = threadIdx.x;
  const int cg = t & 63;
  const int m0 = (t >> 6) * 8;
  const int b  = blockIdx.y;
  const int c0 = blockIdx.x * 256;
  const float* __restrict__ xb =
      x + (size_t)b * (C_N * HW_N) + (size_t)c0 * HW_N;

  const float4* __restrict__ A4 = (const float4*)A + (size_t)b * 1568;
#pragma unroll
  for (int i = 0; i < 7; ++i) {
    int lin = t + i * 256;
    if (lin < 1568) atf4[lin] = A4[lin];
  }
  const float* atf = (const float*)atf4;

  const int hg  = t & 7;     // hw-quad
  const int ccb = t >> 3;    // c-local base, +32 per chunk
  float4 px0, px1, px2, px3, px4, px5, px6, px7;
  const float4 fz = make_float4(0.f, 0.f, 0.f, 0.f);

#define K2_LX(dst, i, h)                                                      \
  dst = *(const float4*)(xb + (size_t)(ccb + (i) * 32) * HW_N + (h))
#define K2_LOAD(h0)                                                           \
  {                                                                           \
    int _h = (h0) + hg * 4;                                                   \
    if (_h < HW_N) {                                                          \
      K2_LX(px0, 0, _h); K2_LX(px1, 1, _h); K2_LX(px2, 2, _h);                \
      K2_LX(px3, 3, _h); K2_LX(px4, 4, _h); K2_LX(px5, 5, _h);                \
      K2_LX(px6, 6, _h); K2_LX(px7, 7, _h);                                   \
    } else {                                                                  \
      px0 = fz; px1 = fz; px2 = fz; px3 = fz;                                 \
      px4 = fz; px5 = fz; px6 = fz; px7 = fz;                                 \
    }                                                                         \
  }
#define K2_ST(v, i)                                                           \
  {                                                                           \
    int cc = ccb + (i) * 32; int g = cc >> 2, sub = cc & 3;                   \
    int r0 = hg * 4;                                                          \
    xsf[(r0 + 0) * 256 + (((g ^ ((r0 + 0) & 15)) << 2) | sub)] = v.x;         \
    xsf[(r0 + 1) * 256 + (((g ^ ((r0 + 1) & 15)) << 2) | sub)] = v.y;         \
    xsf[(r0 + 2) * 256 + (((g ^ ((r0 + 2) & 15)) << 2) | sub)] = v.z;         \
    xsf[(r0 + 3) * 256 + (((g ^ ((r0 + 3) & 15)) << 2) | sub)] = v.w;         \
  }

  float acc[8][4];
#pragma unroll
  for (int j = 0; j < 8; ++j)
#pragma unroll
    for (int r = 0; r < 4; ++r) acc[j][r] = 0.f;

  float* xsf = (float*)xs4;

  K2_LOAD(0);
  for (int h0 = 0; h0 < HW_N; h0 += 32) {
    const int nh4 = (HW_N - h0 < 32) ? (HW_N - h0) / 4 : 8;
    __syncthreads();
    K2_ST(px0, 0); K2_ST(px1, 1); K2_ST(px2, 2); K2_ST(px3, 3);
    K2_ST(px4, 4); K2_ST(px5, 5); K2_ST(px6, 6); K2_ST(px7, 7);
    __syncthreads();
    if (h0 + 32 < HW_N) { K2_LOAD(h0 + 32); }   // in flight across compute
    for (int hq = 0; hq < nh4; ++hq) {
      float4 fv[4];
#pragma unroll
      for (int r2 = 0; r2 < 4; ++r2) {
        int row = hq * 4 + r2;
        fv[r2] = xs4[row][cg ^ (row & 15)];
      }
      const int hbase = h0 + hq * 4;
#pragma unroll
      for (int j = 0; j < 8; ++j) {
        float4 a4 = *(const float4*)(atf + (m0 + j) * HW_N + hbase);  // broadcast
        acc[j][0] = fmaf(fv[0].x, a4.x, acc[j][0]);
        acc[j][1] = fmaf(fv[0].y, a4.x, acc[j][1]);
        acc[j][2] = fmaf(fv[0].z, a4.x, acc[j][2]);
        acc[j][3] = fmaf(fv[0].w, a4.x, acc[j][3]);
        acc[j][0] = fmaf(fv[1].x, a4.y, acc[j][0]);
        acc[j][1] = fmaf(fv[1].y, a4.y, acc[j][1]);
        acc[j][2] = fmaf(fv[1].z, a4.y, acc[j][2]);
        acc[j][3] = fmaf(fv[1].w, a4.y, acc[j][3]);
        acc[j][0] = fmaf(fv[2].x, a4.z, acc[j][0]);
        acc[j][1] = fmaf(fv[2].y, a4.z, acc[j][1]);
        acc[j][2] = fmaf(fv[2].z, a4.z, acc[j][2]);
        acc[j][3] = fmaf(fv[2].w, a4.z, acc[j][3]);
        acc[j][0] = fmaf(fv[3].x, a4.w, acc[j][0]);
        acc[j][1] = fmaf(fv[3].y, a4.w, acc[j][1]);
        acc[j][2] = fmaf(fv[3].z, a4.w, acc[j][2]);
        acc[j][3] = fmaf(fv[3].w, a4.w, acc[j][3]);
      }
    }
  }
  const float s = 1.f / (float)HW_N;
#pragma unroll
  for (int j = 0; j < 8; ++j) {
    float4 o = make_float4(acc[j][0] * s, acc[j][1] * s,
                           acc[j][2] * s, acc[j][3] * s);
    *(float4*)(feats + (size_t)b * K_N + (size_t)(m0 + j) * C_N + c0 + cg * 4) = o;
  }
}

// ---------------------------------------------------------------------------
// K3: partial[kc][b][n] = sum_{k in chunk} feats[b][k] * Wc[n][k]
// grid (7 n-tiles of 64, 128 k-chunks of 512), block 256.
// Block tile 64b x 64n; thread 4x4 strided by 16. Named-reg double buffer.
// ---------------------------------------------------------------------------
#define KC3 512
__global__ __launch_bounds__(256) void k3_cls_part(
    const float* __restrict__ feats, const float* __restrict__ Wc,
    float* __restrict__ partial) {
  __shared__ float fs[64 * 68];   // feats tile [b][k], pad 68
  __shared__ float ws[64 * 68];   // Wc tile [n-local][k], pad 68
  const int t  = threadIdx.x;
  const int bg = t & 15;          // b = bg + 16*i
  const int ng = t >> 4;          // n = n0 + ng + 16*j
  const int n0 = blockIdx.x * 64;
  const size_t k0 = (size_t)blockIdx.y * KC3;

  const int kg   = t & 15;        // k-quad
  const int rowb = t >> 4;        // row base, +16 per i
  const float* fb0 = feats + k0 + kg * 4;
  const float* wb0 = Wc + k0 + kg * 4;
  int nr0 = n0 + rowb, nr1 = n0 + rowb + 16, nr2 = n0 + rowb + 32,
      nr3 = n0 + rowb + 48;
  const size_t nrow0 = (size_t)(nr0 < NC_N ? nr0 : NC_N - 1) * K_N;
  const size_t nrow1 = (size_t)(nr1 < NC_N ? nr1 : NC_N - 1) * K_N;
  const size_t nrow2 = (size_t)(nr2 < NC_N ? nr2 : NC_N - 1) * K_N;
  const size_t nrow3 = (size_t)(nr3 < NC_N ? nr3 : NC_N - 1) * K_N;

  float4 pf0, pf1, pf2, pf3, pw0, pw1, pw2, pw3;
#define K3_LOAD(ks)                                                           \
  pf0 = *(const float4*)(fb0 + (size_t)(rowb +  0) * K_N + (ks) * 64);        \
  pf1 = *(const float4*)(fb0 + (size_t)(rowb + 16) * K_N + (ks) * 64);        \
  pf2 = *(const float4*)(fb0 + (size_t)(rowb + 32) * K_N + (ks) * 64);        \
  pf3 = *(const float4*)(fb0 + (size_t)(rowb + 48) * K_N + (ks) * 64);        \
  pw0 = *(const float4*)(wb0 + nrow0 + (ks) * 64);                            \
  pw1 = *(const float4*)(wb0 + nrow1 + (ks) * 64);                            \
  pw2 = *(const float4*)(wb0 + nrow2 + (ks) * 64);                            \
  pw3 = *(const float4*)(wb0 + nrow3 + (ks) * 64)

  float acc[4][4];
#pragma unroll
  for (int i = 0; i < 4; ++i)
#pragma unroll
    for (int j = 0; j < 4; ++j) acc[i][j] = 0.f;

  K3_LOAD(0);
  for (int ks = 0; ks < KC3 / 64; ++ks) {
    if (ks) __syncthreads();
    *(float4*)(fs + (rowb +  0) * 68 + kg * 4) = pf0;
    *(float4*)(fs + (rowb + 16) * 68 + kg * 4) = pf1;
    *(float4*)(fs + (rowb + 32) * 68 + kg * 4) = pf2;
    *(float4*)(fs + (rowb + 48) * 68 + kg * 4) = pf3;
    *(float4*)(ws + (rowb +  0) * 68 + kg * 4) = pw0;
    *(float4*)(ws + (rowb + 16) * 68 + kg * 4) = pw1;
    *(float4*)(ws + (rowb + 32) * 68 + kg * 4) = pw2;
    *(float4*)(ws + (rowb + 48) * 68 + kg * 4) = pw3;
    __syncthreads();
    if (ks + 1 < KC3 / 64) { K3_LOAD(ks + 1); }   // in flight across compute
#pragma unroll 4
    for (int kq = 0; kq < 16; ++kq) {
      float4 fq[4], wq[4];
#pragma unroll
      for (int i = 0; i < 4; ++i)
        fq[i] = *(const float4*)(fs + (bg + 16 * i) * 68 + kq * 4);
#pragma unroll
      for (int j = 0; j < 4; ++j)
        wq[j] = *(const float4*)(ws + (ng + 16 * j) * 68 + kq * 4);
#pragma unroll
      for (int i = 0; i < 4; ++i)
#pragma unroll
        for (int j = 0; j < 4; ++j) {
          acc[i][j] = fmaf(fq[i].x, wq[j].x, acc[i][j]);
          acc[i][j] = fmaf(fq[i].y, wq[j].y, acc[i][j]);
          acc[i][j] = fmaf(fq[i].z, wq[j].z, acc[i][j]);
          acc[i][j] = fmaf(fq[i].w, wq[j].w, acc[i][j]);
        }
    }
  }
  float* po = partial + (size_t)blockIdx.y * (B_N * NC_N);
#pragma unroll
  for (int i = 0; i < 4; ++i)
#pragma unroll
    for (int j = 0; j < 4; ++j) {
      int n = n0 + ng + 16 * j;
      if (n < NC_N) po[(bg + 16 * i) * NC_N + n] = acc[i][j];
    }
}

// ---------------------------------------------------------------------------
// K4: out[b][n] = bc[n] + sum_kc partial[kc][b][n]   (128 chunks)
// ---------------------------------------------------------------------------
__global__ __launch_bounds__(256) void k4_reduce(
    const float* __restrict__ partial, const float* __restrict__ bc,
    float* __restrict__ out) {
  int idx = blockIdx.x * 256 + threadIdx.x;  // 25344 total
  if (idx >= B_N * NC_N) return;
  int n = idx % NC_N;
  float s = bc[n];
#pragma unroll 8
  for (int kc = 0; kc < 128; ++kc) s += partial[(size_t)kc * (B_N * NC_N) + idx];
  out[idx] = s;
}

// ---------------------------------------------------------------------------
extern "C" void kernel_launch(void* const* d_in, const int* in_sizes, int n_in,
                              void* d_out, int out_size, void* d_ws, size_t ws_size,
                              hipStream_t stream) {
  const float* x  = (const float*)d_in[0];
  const float* Wa = (const float*)d_in[1];
  const float* ba = (const float*)d_in[2];
  const float* Wc = (const float*)d_in[3];
  const float* bc = (const float*)d_in[4];
  float* out = (float*)d_out;

  char* ws = (char*)d_ws;
  // lifetimes: zpart [k1..k1b], A [k1b..k2], feats [k2..k3],
  // partial [k3..k4] reuses the (dead) zpart region. Peak use < 32 MiB.
  float* A       = (float*)(ws);                 // [0, 1.61 MB)
  float* zpart   = (float*)(ws + (2u  << 20));   // 8*64*32*196*4 = 12.85 MB
  float* feats   = (float*)(ws + (15u << 20));   // 64*65536*4    = 16.8 MB
  float* partial = (float*)(ws + (2u  << 20));   // 128*25344*4   = 12.97 MB
  (void)ws_size; (void)in_sizes; (void)n_in; (void)out_size;

  hipLaunchKernelGGL(k1_attn_part, dim3(2, 64, 8), dim3(256), 0, stream,
                     x, Wa, zpart);
  hipLaunchKernelGGL(k1b_sigmoid, dim3((B_N * M_N * HW_N + 255) / 256),
                     dim3(256), 0, stream, zpart, ba, A);
  hipLaunchKernelGGL(k2_bap, dim3(8, 64), dim3(256), 0, stream, x, A, feats);
  hipLaunchKernelGGL(k3_cls_part, dim3(7, 128), dim3(256), 0, stream,
                     feats, Wc, partial);
  hipLaunchKernelGGL(k4_reduce, dim3(99), dim3(256), 0, stream,
                     partial, bc, out);
}

// Round 5
// 299.422 us; speedup vs baseline: 1.2736x; 1.0942x over previous
//
#include <hip/hip_runtime.h>
#include <hip/hip_bf16.h>
#include <cstdint>

#define B_N 64
#define C_N 2048
#define HW_N 196
#define HWP 224          // zero-padded hw length for A (7 k-steps of 32)
#define M_N 32
#define NC_N 396
#define K_N 65536        // M_N * C_N

typedef __attribute__((ext_vector_type(8))) short bf16x8;
typedef __attribute__((ext_vector_type(4))) float f32x4;

__device__ inline short f2bf(float x) {   // RNE fp32 -> bf16
  union { float f; unsigned u; } v; v.f = x;
  unsigned r = (v.u + 0x7FFFu + ((v.u >> 16) & 1u)) >> 16;
  return (short)r;
}

// ---------------------------------------------------------------------------
// K1: Apad[b][m][hwp] = sigmoid(sum_c x[b][c][hw]*Wa[m][c] + ba[m]) (0 if hw>=196)
// grid(14,64), block 256. MFMA 16x16x32 bf16: A=Wa[m][c] (2 m-frags),
// B=x[c][hw] (natural row-major for both!). 4 waves split c (512 each),
// no barriers in the K-loop; one LDS reduction at the end.
// ---------------------------------------------------------------------------
__global__ __launch_bounds__(256) void k1_attn(
    const float* __restrict__ x, const float* __restrict__ Wa,
    const float* __restrict__ ba, short* __restrict__ Apad) {
  __shared__ float red[4][8][64];
  const int t = threadIdx.x;
  const int w = t >> 6, lane = t & 63, lq = lane >> 4, ln = lane & 15;
  const int b = blockIdx.y;
  const int hw0 = blockIdx.x * 16;
  const int hwl = hw0 + ln;
  const int hwc = hwl < HW_N ? hwl : HW_N - 1;        // clamp: garbage cols are masked
  const float* __restrict__ xb  = x + (size_t)b * (C_N * HW_N) + hwc;
  const float* __restrict__ wa0 = Wa + (size_t)ln * C_N;
  const float* __restrict__ wa1 = Wa + (size_t)(16 + ln) * C_N;

  f32x4 d0 = {0.f, 0.f, 0.f, 0.f}, d1 = {0.f, 0.f, 0.f, 0.f};
  const int cw = w * 512 + lq * 8;    // this wave+quad's k-base
#pragma unroll 2
  for (int s = 0; s < 16; ++s) {
    const int cc = cw + s * 32;
    float4 a0l = *(const float4*)(wa0 + cc);
    float4 a0h = *(const float4*)(wa0 + cc + 4);
    float4 a1l = *(const float4*)(wa1 + cc);
    float4 a1h = *(const float4*)(wa1 + cc + 4);
    bf16x8 af0, af1, bfr;
    af0[0]=f2bf(a0l.x); af0[1]=f2bf(a0l.y); af0[2]=f2bf(a0l.z); af0[3]=f2bf(a0l.w);
    af0[4]=f2bf(a0h.x); af0[5]=f2bf(a0h.y); af0[6]=f2bf(a0h.z); af0[7]=f2bf(a0h.w);
    af1[0]=f2bf(a1l.x); af1[1]=f2bf(a1l.y); af1[2]=f2bf(a1l.z); af1[3]=f2bf(a1l.w);
    af1[4]=f2bf(a1h.x); af1[5]=f2bf(a1h.y); af1[6]=f2bf(a1h.z); af1[7]=f2bf(a1h.w);
#pragma unroll
    for (int j = 0; j < 8; ++j)
      bfr[j] = f2bf(xb[(size_t)(cc + j) * HW_N]);
    d0 = __builtin_amdgcn_mfma_f32_16x16x32_bf16(af0, bfr, d0, 0, 0, 0);
    d1 = __builtin_amdgcn_mfma_f32_16x16x32_bf16(af1, bfr, d1, 0, 0, 0);
  }
  // cross-wave k-reduction
  red[w][0][lane] = d0[0]; red[w][1][lane] = d0[1];
  red[w][2][lane] = d0[2]; red[w][3][lane] = d0[3];
  red[w][4][lane] = d1[0]; red[w][5][lane] = d1[1];
  red[w][6][lane] = d1[2]; red[w][7][lane] = d1[3];
  __syncthreads();
#pragma unroll
  for (int rep = 0; rep < 2; ++rep) {
    int id = t + rep * 256;                  // 0..511 = (lane 0..63) x (fr 0..7)
    int lr = id >> 3, fr = id & 7;
    float ssum = red[0][fr][lr] + red[1][fr][lr] + red[2][fr][lr] + red[3][fr][lr];
    int m  = (fr >> 2) * 16 + (lr >> 4) * 4 + (fr & 3);   // C-layout: row=quad*4+reg
    int hw = hw0 + (lr & 15);                             // col=lane&15
    float zz = ssum + ba[m];
    float av = (hw < HW_N) ? 1.f / (1.f + __expf(-zz)) : 0.f;
    Apad[((size_t)b * M_N + m) * HWP + hw] = f2bf(av);
  }
}

// ---------------------------------------------------------------------------
// K2: featsb[b][m*2048+c] = bf16( (1/196) sum_hw x[b][c][hw]*A[b][m][hw] )
// grid(32,64), block 256. k=hw (7 steps of 32, Apad zero-padded).
// A-frags: raw bf16 loads from Apad (no cvt); B-frags: x row-major dwordx4.
// No LDS, no barriers. Tail step predicated (x ends page-exact).
// ---------------------------------------------------------------------------
__global__ __launch_bounds__(256) void k2_bap(
    const float* __restrict__ x, const short* __restrict__ Apad,
    short* __restrict__ featsb) {
  const int t = threadIdx.x;
  const int w = t >> 6, lane = t & 63, lq = lane >> 4, ln = lane & 15;
  const int b = blockIdx.y;
  const int c = blockIdx.x * 64 + w * 16 + ln;
  const float* __restrict__ xrow = x + (size_t)b * (C_N * HW_N) + (size_t)c * HW_N;
  const short* __restrict__ ap0 = Apad + ((size_t)b * M_N + ln) * HWP + lq * 8;
  const short* __restrict__ ap1 = ap0 + 16 * HWP;

  f32x4 d0 = {0.f, 0.f, 0.f, 0.f}, d1 = {0.f, 0.f, 0.f, 0.f};
#pragma unroll
  for (int s = 0; s < 7; ++s) {
    bf16x8 a0 = *(const bf16x8*)(ap0 + s * 32);
    bf16x8 a1 = *(const bf16x8*)(ap1 + s * 32);
    bf16x8 bfr;
    const int h = s * 32 + lq * 8;
    if (s < 6) {
      float4 b0 = *(const float4*)(xrow + h);
      float4 b1 = *(const float4*)(xrow + h + 4);
      bfr[0]=f2bf(b0.x); bfr[1]=f2bf(b0.y); bfr[2]=f2bf(b0.z); bfr[3]=f2bf(b0.w);
      bfr[4]=f2bf(b1.x); bfr[5]=f2bf(b1.y); bfr[6]=f2bf(b1.z); bfr[7]=f2bf(b1.w);
    } else {
      // hw 192..223: only quad 0 j0..3 (hw 192..195) exists; rest hit A=0 pad
      float4 b0 = make_float4(0.f, 0.f, 0.f, 0.f);
      if (lq == 0) b0 = *(const float4*)(xrow + h);
      bfr[0]=f2bf(b0.x); bfr[1]=f2bf(b0.y); bfr[2]=f2bf(b0.z); bfr[3]=f2bf(b0.w);
      bfr[4]=0; bfr[5]=0; bfr[6]=0; bfr[7]=0;
    }
    d0 = __builtin_amdgcn_mfma_f32_16x16x32_bf16(a0, bfr, d0, 0, 0, 0);
    d1 = __builtin_amdgcn_mfma_f32_16x16x32_bf16(a1, bfr, d1, 0, 0, 0);
  }
  const float sc = 1.f / (float)HW_N;
  short* fb = featsb + (size_t)b * K_N + c;
#pragma unroll
  for (int r = 0; r < 4; ++r) {
    int m0 = lq * 4 + r;
    fb[(size_t)m0 * C_N]        = f2bf(d0[r] * sc);
    fb[(size_t)(16 + m0) * C_N] = f2bf(d1[r] * sc);
  }
}

// ---------------------------------------------------------------------------
// K3: partial[kc][b][n] = sum_{k in chunk} feats[b][k] * Wc[n][k]
// grid(7,128), block 256, k-chunk 512. Pure streaming MFMA: 4 b-frags (64 b,
// raw bf16) x 1 Wc-frag per wave; waves cover 64 n. No LDS, no barriers.
// ---------------------------------------------------------------------------
__global__ __launch_bounds__(256) void k3_cls(
    const short* __restrict__ featsb, const float* __restrict__ Wc,
    float* __restrict__ partial) {
  const int t = threadIdx.x;
  const int w = t >> 6, lane = t & 63, lq = lane >> 4, ln = lane & 15;
  const int n = blockIdx.x * 64 + w * 16 + ln;
  const int nc = n < NC_N ? n : NC_N - 1;
  const size_t k0 = (size_t)blockIdx.y * 512;
  const float* __restrict__ wrow = Wc + (size_t)nc * K_N + k0 + lq * 8;
  const short* __restrict__ f0 = featsb + k0 + lq * 8 + (size_t)ln * K_N;

  f32x4 acc0 = {0.f,0.f,0.f,0.f}, acc1 = {0.f,0.f,0.f,0.f};
  f32x4 acc2 = {0.f,0.f,0.f,0.f}, acc3 = {0.f,0.f,0.f,0.f};
#pragma unroll 4
  for (int s = 0; s < 16; ++s) {
    const int kk = s * 32;
    float4 w0 = *(const float4*)(wrow + kk);
    float4 w1 = *(const float4*)(wrow + kk + 4);
    bf16x8 bfr;
    bfr[0]=f2bf(w0.x); bfr[1]=f2bf(w0.y); bfr[2]=f2bf(w0.z); bfr[3]=f2bf(w0.w);
    bfr[4]=f2bf(w1.x); bfr[5]=f2bf(w1.y); bfr[6]=f2bf(w1.z); bfr[7]=f2bf(w1.w);
    bf16x8 a0 = *(const bf16x8*)(f0 + kk);
    bf16x8 a1 = *(const bf16x8*)(f0 + (size_t)16 * K_N + kk);
    bf16x8 a2 = *(const bf16x8*)(f0 + (size_t)32 * K_N + kk);
    bf16x8 a3 = *(const bf16x8*)(f0 + (size_t)48 * K_N + kk);
    acc0 = __builtin_amdgcn_mfma_f32_16x16x32_bf16(a0, bfr, acc0, 0, 0, 0);
    acc1 = __builtin_amdgcn_mfma_f32_16x16x32_bf16(a1, bfr, acc1, 0, 0, 0);
    acc2 = __builtin_amdgcn_mfma_f32_16x16x32_bf16(a2, bfr, acc2, 0, 0, 0);
    acc3 = __builtin_amdgcn_mfma_f32_16x16x32_bf16(a3, bfr, acc3, 0, 0, 0);
  }
  if (n < NC_N) {
    float* po = partial + (size_t)blockIdx.y * (B_N * NC_N) + n;
#pragma unroll
    for (int r = 0; r < 4; ++r) {
      int br = lq * 4 + r;                    // b within 16-tile
      po[(size_t)br * NC_N]        = acc0[r];
      po[(size_t)(16 + br) * NC_N] = acc1[r];
      po[(size_t)(32 + br) * NC_N] = acc2[r];
      po[(size_t)(48 + br) * NC_N] = acc3[r];
    }
  }
}

// ---------------------------------------------------------------------------
// K4: out[b][n] = bc[n] + sum_kc partial[kc][b][n]   (128 chunks)
// ---------------------------------------------------------------------------
__global__ __launch_bounds__(256) void k4_reduce(
    const float* __restrict__ partial, const float* __restrict__ bc,
    float* __restrict__ out) {
  int idx = blockIdx.x * 256 + threadIdx.x;  // 25344 total
  if (idx >= B_N * NC_N) return;
  int n = idx % NC_N;
  float s = bc[n];
#pragma unroll 8
  for (int kc = 0; kc < 128; ++kc) s += partial[(size_t)kc * (B_N * NC_N) + idx];
  out[idx] = s;
}

// ---------------------------------------------------------------------------
extern "C" void kernel_launch(void* const* d_in, const int* in_sizes, int n_in,
                              void* d_out, int out_size, void* d_ws, size_t ws_size,
                              hipStream_t stream) {
  const float* x  = (const float*)d_in[0];
  const float* Wa = (const float*)d_in[1];
  const float* ba = (const float*)d_in[2];
  const float* Wc = (const float*)d_in[3];
  const float* bc = (const float*)d_in[4];
  float* out = (float*)d_out;

  char* wsb = (char*)d_ws;
  short* Apad    = (short*)(wsb);                // 64*32*224*2   = 0.92 MB
  short* featsb  = (short*)(wsb + (1u  << 20));  // 64*65536*2    = 8.39 MB
  float* partial = (float*)(wsb + (10u << 20));  // 128*25344*4   = 12.98 MB
  (void)ws_size; (void)in_sizes; (void)n_in; (void)out_size;

  hipLaunchKernelGGL(k1_attn, dim3(14, 64), dim3(256), 0, stream,
                     x, Wa, ba, Apad);
  hipLaunchKernelGGL(k2_bap, dim3(32, 64), dim3(256), 0, stream,
                     x, Apad, featsb);
  hipLaunchKernelGGL(k3_cls, dim3(7, 128), dim3(256), 0, stream,
                     featsb, Wc, partial);
  hipLaunchKernelGGL(k4_reduce, dim3(99), dim3(256), 0, stream,
                     partial, bc, out);
}